// Round 6
// baseline (114.821 us; speedup 1.0000x reference)
//
#include <hip/hip_runtime.h>

#define N2 16384
#define N1 65536

// ---- output layout (float offsets) ----
#define OUT_AIM 7225344         // 21*21*N2
#define OUT_LD  14450688        // 2*21*21*N2
#define OUT_ZRE 14450689
#define OUT_ZIM 14794753        // OUT_ZRE + 21*N2

// ---- LDS layout (float offsets), TILE_J = 64, slim SC ----
#define L_T2R  0                // [20][64]
#define L_T2I  1280
#define L_M2   2560             // [c:2][u:4][64]
#define L_SC   3072             // [idx:12][u:4][64]
//  y<4 : 0..3 t1r[b], 4..7 t1i[b], 8 p1r[y], 9 p1i[y], 10 i0r[y], 11 i0i[y]
//  y==4: 0..3 p1r[b], 4..7 p1i[b], 8 is1r,   9 is1i
#define L_IS2R 6144             // [64]
#define L_IS2I 6208
#define L_RED  6272             // [4]
#define L_TOT  6276             // 25.1 KB -> 4+ blocks/CU co-resident

#define SC(idx, uu, jj) lds[L_SC + (((idx)*4 + (uu)) * 64) + (jj)]

// grid = (N2/64, 6), block = 256 threads (4 waves).
// blockIdx.y picks a 4-row slice of the 21 output rows: p = y*4 + wave.
// Slices share a fixed a_p = y, so only a 12-entry scatter stash is needed.
// Phase 1 (all 256 threads): stage-0/1/2 Schur chain per (u, jl) into LDS
// (redundant across 6 slices; inputs L2/L3-resident; logf only in y==0).
// Phase 2: wave g emits output row p = y*4 + g (slice 5: row 20 only).
__global__ __launch_bounds__(256, 4) void fused_kernel(
    const float* __restrict__ l00r, const float* __restrict__ l00i,
    const float* __restrict__ l01r, const float* __restrict__ l01i,
    const float* __restrict__ l02r, const float* __restrict__ l02i,
    const float* __restrict__ l11r, const float* __restrict__ l11i,
    const float* __restrict__ l12r, const float* __restrict__ l12i,
    const float* __restrict__ l22r, const float* __restrict__ l22i,
    const float* __restrict__ zre,  const float* __restrict__ zim,
    float* __restrict__ out, double* __restrict__ ld_partial)
{
    __shared__ float lds[L_TOT];
    const int t   = threadIdx.x;
    const int jl  = t & 63;
    const int u   = t >> 6;                         // wave id / u-chunk 0..3
    const int j0  = blockIdx.x * 64;
    const int y   = blockIdx.y;                     // row slice 0..5
    const bool y0 = (y == 0);
    float ld = 0.f;

    // ================= phase 1: stage 0/1/2 per (u, jl) =================
    {
        const int m = u * N2 + (j0 + jl);

        float i0r[4], i0i[4], t1r[4], t1i[4], p1r[4], p1i[4];
        float m1r = 0.f, m1i = 0.f;
#pragma unroll
        for (int k = 0; k < 4; ++k) {
            const int i = k * N1 + m;
            const float ar = l00r[i], ai = l00i[i];
            const float br = l01r[i], bi = l01i[i];
            const float d  = ar*ar + ai*ai;
            const float rd = 1.f / d;
            if (y0) ld += 0.5f * logf(d);           // log|lam00|
            const float xr = ar * rd, xi = -ai * rd;
            i0r[k] = xr; i0i[k] = xi;
            const float tr = br*xr - bi*xi;         // T1 = lam01/lam00
            const float ti = br*xi + bi*xr;
            t1r[k] = tr; t1i[k] = ti;
            m1r += br*tr + bi*ti;                   // conj(lam01)*T1
            m1i += br*ti - bi*tr;
        }
        const float s1r = l11r[m] - m1r;
        const float s1i = l11i[m] - m1i;
        const float ds1 = s1r*s1r + s1i*s1i;
        if (y0) ld += 0.5f * logf(ds1);             // log|S1|
        const float rds1 = 1.f / ds1;
        const float is1r = s1r * rds1, is1i = -s1i * rds1;
#pragma unroll
        for (int k = 0; k < 4; ++k) {
            p1r[k] = t1r[k]*is1r - t1i[k]*is1i;     // P1 = T1/S1
            p1i[k] = t1r[k]*is1i + t1i[k]*is1r;
        }

        // stage-2 B column: Bcol[a<4]=lam02[a*N1+m], Bcol[4]=lam12[m]
        float bcr[5], bci[5];
#pragma unroll
        for (int a = 0; a < 4; ++a) { bcr[a] = l02r[a*N1+m]; bci[a] = l02i[a*N1+m]; }
        bcr[4] = l12r[m]; bci[4] = l12i[m];

        // W = sum_{b<4} Bcol[b]*conj(T1[b]) - Bcol[4]
        float wr = -bcr[4], wi = -bci[4];
#pragma unroll
        for (int b = 0; b < 4; ++b) {
            wr += bcr[b]*t1r[b] + bci[b]*t1i[b];
            wi += bci[b]*t1r[b] - bcr[b]*t1i[b];
        }
        // T2 rows q = a*4+u
        float ur[5], ui[5];
#pragma unroll
        for (int a = 0; a < 4; ++a) {
            ur[a] = p1r[a]*wr - p1i[a]*wi + bcr[a]*i0r[a] - bci[a]*i0i[a];
            ui[a] = p1r[a]*wi + p1i[a]*wr + bcr[a]*i0i[a] + bci[a]*i0r[a];
        }
        {
            float vr = bcr[4]*is1r - bci[4]*is1i;   // Bcol[4]/S1
            float vi = bcr[4]*is1i + bci[4]*is1r;
#pragma unroll
            for (int b = 0; b < 4; ++b) {           // - Bcol[b]*conj(P1[b])
                vr -= bcr[b]*p1r[b] + bci[b]*p1i[b];
                vi -= bci[b]*p1r[b] - bcr[b]*p1i[b];
            }
            ur[4] = vr; ui[4] = vi;
        }
        float m2r = 0.f, m2i = 0.f;
#pragma unroll
        for (int a = 0; a < 5; ++a) {
            lds[L_T2R + (a*4+u)*64 + jl] = ur[a];
            lds[L_T2I + (a*4+u)*64 + jl] = ui[a];
            m2r += bcr[a]*ur[a] + bci[a]*ui[a];     // conj(B)*T2
            m2i += bcr[a]*ui[a] - bci[a]*ur[a];
        }
        lds[L_M2 + (0*4+u)*64 + jl] = m2r;
        lds[L_M2 + (1*4+u)*64 + jl] = m2i;

        if (y < 4) {                                // slice rows have a_p = y
#pragma unroll
            for (int b = 0; b < 4; ++b) {
                SC(b,   u, jl) = t1r[b];  SC(4+b, u, jl) = t1i[b];
            }
            SC(8,  u, jl) = p1r[y];  SC(9,  u, jl) = p1i[y];
            SC(10, u, jl) = i0r[y];  SC(11, u, jl) = i0i[y];
        } else if (y == 4) {                        // rows 16..19: a_p = 4
#pragma unroll
            for (int b = 0; b < 4; ++b) {
                SC(b,   u, jl) = p1r[b];  SC(4+b, u, jl) = p1i[b];
            }
            SC(8, u, jl) = is1r;  SC(9, u, jl) = is1i;
        }                                           // y == 5: none needed
    }
    __syncthreads();

    // ================= phase 1.5: S2 per column =================
    if (t < 64) {
        float s2r = l22r[j0 + t], s2i = l22i[j0 + t];
#pragma unroll
        for (int uu = 0; uu < 4; ++uu) {
            s2r -= lds[L_M2 + (0*4+uu)*64 + t];
            s2i -= lds[L_M2 + (1*4+uu)*64 + t];
        }
        const float ds2  = s2r*s2r + s2i*s2i;
        const float rds2 = 1.f / ds2;
        lds[L_IS2R + t] =  s2r * rds2;
        lds[L_IS2I + t] = -s2i * rds2;
        if (y0) ld += 0.5f * logf(ds2);             // log|S2|
    }
    __syncthreads();

    // ================= phase 2: wave g emits row p = y*4 + g =================
    const int g = u;                                // wave group 0..3
    const int p = y * 4 + g;                        // output row
    const int j = j0 + jl;

    if (p <= 20) {
        const float is2r = lds[L_IS2R + jl];
        const float is2i = lds[L_IS2I + jl];
        float zar = 0.f, zai = 0.f;

        if (p == 20) {
#pragma unroll
            for (int q = 0; q < 21; ++q) {
                float ar, ai;
                if (q < 20) {
                    const float tqr = lds[L_T2R + q*64 + jl];
                    const float tqi = lds[L_T2I + q*64 + jl];
                    ar = -(tqr*is2r - tqi*is2i);    // -conj(P2[q])
                    ai =  (tqr*is2i + tqi*is2r);
                } else { ar = is2r; ai = is2i; }    // 1/S2
                __builtin_nontemporal_store(ar, out + (p*21+q)*N2 + j);
                __builtin_nontemporal_store(ai, out + OUT_AIM + (p*21+q)*N2 + j);
                const float zqr = zre[q*N2+j], zqi = zim[q*N2+j];
                zar += zqr*ar - zqi*ai;
                zai += zqr*ai + zqi*ar;
            }
        } else {
            const float tpr = lds[L_T2R + p*64 + jl];
            const float tpi = lds[L_T2I + p*64 + jl];
            const float ppr = tpr*is2r - tpi*is2i;  // P2[p]
            const float ppi = tpr*is2i + tpi*is2r;
            // scatter addends for q = b*4 + g   (u_p = g, a_p = y)
            float sar[5], sai[5];
            if (y < 4) {
                const float par = SC(8, g, jl), pai = SC(9, g, jl);  // P1[y]
#pragma unroll
                for (int b = 0; b < 4; ++b) {
                    const float tbr = SC(b, g, jl), tbi = SC(4+b, g, jl);
                    sar[b] = par*tbr + pai*tbi;     // P1[y]*conj(T1[b])
                    sai[b] = pai*tbr - par*tbi;
                }
                sar[y] += SC(10, g, jl);            // + 1/lam00
                sai[y] += SC(11, g, jl);
                sar[4] = -par; sai[4] = -pai;       // -P1[y]
            } else {                                // y == 4
#pragma unroll
                for (int b = 0; b < 4; ++b) {       // -conj(P1[b])
                    sar[b] = -SC(b,   g, jl);
                    sai[b] =  SC(4+b, g, jl);
                }
                sar[4] = SC(8, g, jl);              // 1/S1
                sai[4] = SC(9, g, jl);
            }
#pragma unroll
            for (int q = 0; q < 21; ++q) {
                float ar, ai;
                if (q < 20) {
                    const float tqr = lds[L_T2R + q*64 + jl];
                    const float tqi = lds[L_T2I + q*64 + jl];
                    ar = ppr*tqr + ppi*tqi;         // P2[p]*conj(T2[q])
                    ai = ppi*tqr - ppr*tqi;
                    if ((q & 3) == g) { ar += sar[q>>2]; ai += sai[q>>2]; }
                } else { ar = -ppr; ai = -ppi; }    // -P2[p]
                __builtin_nontemporal_store(ar, out + (p*21+q)*N2 + j);
                __builtin_nontemporal_store(ai, out + OUT_AIM + (p*21+q)*N2 + j);
                const float zqr = zre[q*N2+j], zqi = zim[q*N2+j];
                zar += zqr*ar - zqi*ai;
                zai += zqr*ai + zqi*ar;
            }
        }
        __builtin_nontemporal_store(zar, out + OUT_ZRE + p*N2 + j);
        __builtin_nontemporal_store(zai, out + OUT_ZIM + p*N2 + j);
    }

    // ================= logdet block reduction (y==0 only) =================
    if (y0) {
        float v = ld;
#pragma unroll
        for (int off = 32; off > 0; off >>= 1) v += __shfl_down(v, off, 64);
        if (jl == 0) lds[L_RED + g] = v;            // disjoint LDS region
        __syncthreads();
        if (t == 0) {
            double s = 0.0;
#pragma unroll
            for (int w = 0; w < 4; ++w) s += (double)lds[L_RED + w];
            ld_partial[blockIdx.x] = s;
        }
    }
}

__global__ void finalize_kernel(const double* __restrict__ part,
                                float* __restrict__ out) {
    double v = part[threadIdx.x];                   // 256 partials
#pragma unroll
    for (int off = 32; off > 0; off >>= 1) v += __shfl_down(v, off, 64);
    __shared__ double wsum[4];
    if ((threadIdx.x & 63) == 0) wsum[threadIdx.x >> 6] = v;
    __syncthreads();
    if (threadIdx.x == 0)
        out[OUT_LD] = (float)(wsum[0] + wsum[1] + wsum[2] + wsum[3]);
}

extern "C" void kernel_launch(void* const* d_in, const int* in_sizes, int n_in,
                              void* d_out, int out_size, void* d_ws, size_t ws_size,
                              hipStream_t stream)
{
    const float* l00r = (const float*)d_in[0];
    const float* l00i = (const float*)d_in[1];
    const float* l01r = (const float*)d_in[2];
    const float* l01i = (const float*)d_in[3];
    const float* l02r = (const float*)d_in[4];
    const float* l02i = (const float*)d_in[5];
    const float* l11r = (const float*)d_in[6];
    const float* l11i = (const float*)d_in[7];
    const float* l12r = (const float*)d_in[8];
    const float* l12i = (const float*)d_in[9];
    const float* l22r = (const float*)d_in[10];
    const float* l22i = (const float*)d_in[11];
    const float* zre  = (const float*)d_in[12];
    const float* zim  = (const float*)d_in[13];
    float*  out        = (float*)d_out;
    double* ld_partial = (double*)d_ws;             // 256 doubles, written each call

    fused_kernel<<<dim3(N2/64, 6), dim3(256), 0, stream>>>(
        l00r,l00i,l01r,l01i,l02r,l02i,l11r,l11i,l12r,l12i,l22r,l22i,
        zre,zim, out, ld_partial);
    finalize_kernel<<<1, 256, 0, stream>>>(ld_partial, out);
}

// Round 8
// 113.449 us; speedup vs baseline: 1.0121x; 1.0121x over previous
//
#include <hip/hip_runtime.h>

#define N2 16384
#define N1 65536

typedef float vf4 __attribute__((ext_vector_type(4)));

// ---- output layout (float offsets) ----
#define OUT_AIM 7225344         // 21*21*N2
#define OUT_LD  14450688        // 2*21*21*N2
#define OUT_ZRE 14450689
#define OUT_ZIM 14794753        // OUT_ZRE + 21*N2

// ---- LDS layout (float offsets), TILE_J = 64 ----
#define L_T2R  0                // [20][64]
#define L_T2I  1280
#define L_M2   2560             // [c:2][u:4][64]
#define L_SC   3072             // [idx:26][u:4][64]
//   idx 0..3  t1r[b], 4..7  t1i[b], 8..11 p1r[b], 12..15 p1i[b],
//   idx 16..19 i0r[k], 20..23 i0i[k], 24 is1r, 25 is1i
#define L_IS2R 9728             // [64]
#define L_IS2I 9792
#define L_RED  9856             // [7]
#define L_TOT  9864             // 38.5 KB

#define SC(idx, u, jl) lds[L_SC + (((idx)*4 + (u)) * 64) + (jl)]

// grid = (N2/64, 3), block = 448 threads (7 waves).
// Phase 1 (t<256): stage-0/1/2 Schur chain per (u, jl) into LDS (redundant
// across the 3 y-slices; inputs are L2/L3-resident; logf only in y==0).
// Phase 2: wave g emits row p = y*7+g; lane owns 4 adjacent columns with a
// quarter-wave q-split -> every A-store / z-load / T2-read is a 16B vector op
// (A-stores: 64 lanes x 16B = 1 KB per instruction, the m13 peak-BW width).
__global__ __launch_bounds__(448, 4) void fused_kernel(
    const float* __restrict__ l00r, const float* __restrict__ l00i,
    const float* __restrict__ l01r, const float* __restrict__ l01i,
    const float* __restrict__ l02r, const float* __restrict__ l02i,
    const float* __restrict__ l11r, const float* __restrict__ l11i,
    const float* __restrict__ l12r, const float* __restrict__ l12i,
    const float* __restrict__ l22r, const float* __restrict__ l22i,
    const float* __restrict__ zre,  const float* __restrict__ zim,
    float* __restrict__ out, double* __restrict__ ld_partial)
{
    __shared__ float lds[L_TOT];
    const int t   = threadIdx.x;
    const int jl  = t & 63;
    const int j0  = blockIdx.x * 64;
    const bool y0 = (blockIdx.y == 0);
    float ld = 0.f;

    // ================= phase 1: stage 0/1/2 per (u, jl) =================
    if (t < 256) {
        const int u = t >> 6;
        const int m = u * N2 + (j0 + jl);

        float i0r[4], i0i[4], t1r[4], t1i[4], p1r[4], p1i[4];
        float m1r = 0.f, m1i = 0.f;
#pragma unroll
        for (int k = 0; k < 4; ++k) {
            const int i = k * N1 + m;
            const float ar = l00r[i], ai = l00i[i];
            const float br = l01r[i], bi = l01i[i];
            const float d  = ar*ar + ai*ai;
            const float rd = 1.f / d;
            if (y0) ld += 0.5f * logf(d);           // log|lam00|
            const float xr = ar * rd, xi = -ai * rd;
            i0r[k] = xr; i0i[k] = xi;
            const float tr = br*xr - bi*xi;         // T1 = lam01/lam00
            const float ti = br*xi + bi*xr;
            t1r[k] = tr; t1i[k] = ti;
            m1r += br*tr + bi*ti;                   // conj(lam01)*T1
            m1i += br*ti - bi*tr;
        }
        const float s1r = l11r[m] - m1r;
        const float s1i = l11i[m] - m1i;
        const float ds1 = s1r*s1r + s1i*s1i;
        if (y0) ld += 0.5f * logf(ds1);             // log|S1|
        const float rds1 = 1.f / ds1;
        const float is1r = s1r * rds1, is1i = -s1i * rds1;
#pragma unroll
        for (int k = 0; k < 4; ++k) {
            p1r[k] = t1r[k]*is1r - t1i[k]*is1i;     // P1 = T1/S1
            p1i[k] = t1r[k]*is1i + t1i[k]*is1r;
        }

        // stage-2 B column: Bcol[a<4]=lam02[a*N1+m], Bcol[4]=lam12[m]
        float bcr[5], bci[5];
#pragma unroll
        for (int a = 0; a < 4; ++a) { bcr[a] = l02r[a*N1+m]; bci[a] = l02i[a*N1+m]; }
        bcr[4] = l12r[m]; bci[4] = l12i[m];

        // W = sum_{b<4} Bcol[b]*conj(T1[b]) - Bcol[4]
        float wr = -bcr[4], wi = -bci[4];
#pragma unroll
        for (int b = 0; b < 4; ++b) {
            wr += bcr[b]*t1r[b] + bci[b]*t1i[b];
            wi += bci[b]*t1r[b] - bcr[b]*t1i[b];
        }
        // T2 rows q = a*4+u
        float ur[5], ui[5];
#pragma unroll
        for (int a = 0; a < 4; ++a) {
            ur[a] = p1r[a]*wr - p1i[a]*wi + bcr[a]*i0r[a] - bci[a]*i0i[a];
            ui[a] = p1r[a]*wi + p1i[a]*wr + bcr[a]*i0i[a] + bci[a]*i0r[a];
        }
        {
            float vr = bcr[4]*is1r - bci[4]*is1i;   // Bcol[4]/S1
            float vi = bcr[4]*is1i + bci[4]*is1r;
#pragma unroll
            for (int b = 0; b < 4; ++b) {           // - Bcol[b]*conj(P1[b])
                vr -= bcr[b]*p1r[b] + bci[b]*p1i[b];
                vi -= bci[b]*p1r[b] - bcr[b]*p1i[b];
            }
            ur[4] = vr; ui[4] = vi;
        }
        float m2r = 0.f, m2i = 0.f;
#pragma unroll
        for (int a = 0; a < 5; ++a) {
            lds[L_T2R + (a*4+u)*64 + jl] = ur[a];
            lds[L_T2I + (a*4+u)*64 + jl] = ui[a];
            m2r += bcr[a]*ur[a] + bci[a]*ui[a];     // conj(B)*T2
            m2i += bcr[a]*ui[a] - bci[a]*ur[a];
        }
        lds[L_M2 + (0*4+u)*64 + jl] = m2r;
        lds[L_M2 + (1*4+u)*64 + jl] = m2i;
#pragma unroll
        for (int b = 0; b < 4; ++b) {
            SC(b,      u, jl) = t1r[b];  SC(4+b,  u, jl) = t1i[b];
            SC(8+b,    u, jl) = p1r[b];  SC(12+b, u, jl) = p1i[b];
            SC(16+b,   u, jl) = i0r[b];  SC(20+b, u, jl) = i0i[b];
        }
        SC(24, u, jl) = is1r;  SC(25, u, jl) = is1i;
    }
    __syncthreads();

    // ================= phase 1.5: S2 per column =================
    if (t < 64) {
        float s2r = l22r[j0 + t], s2i = l22i[j0 + t];
#pragma unroll
        for (int uu = 0; uu < 4; ++uu) {
            s2r -= lds[L_M2 + (0*4+uu)*64 + t];
            s2i -= lds[L_M2 + (1*4+uu)*64 + t];
        }
        const float ds2  = s2r*s2r + s2i*s2i;
        const float rds2 = 1.f / ds2;
        lds[L_IS2R + t] =  s2r * rds2;
        lds[L_IS2I + t] = -s2i * rds2;
        if (y0) ld += 0.5f * logf(ds2);             // log|S2|
    }
    __syncthreads();

    // ===== phase 2: row p; lane = (h: q-offset 0..3, ci: 4-column group) =====
    const int g  = t >> 6;                          // wave group 0..6
    const int p  = blockIdx.y * 7 + g;              // output row 0..20
    const int l  = t & 63;
    const int h  = l >> 4;                          // q = 4*qi + h
    const int c4 = (l & 15) * 4;                    // first of 4 columns
    const int j4 = j0 + c4;

    const vf4 is2r = *(const vf4*)&lds[L_IS2R + c4];
    const vf4 is2i = *(const vf4*)&lds[L_IS2I + c4];

    float zar[4] = {0,0,0,0}, zai[4] = {0,0,0,0};

    float ppr[4], ppi[4];                           // P2[p] per column (p<20)
    float sar[4], sai[4];                           // scatter addends (h==u_p)
    const int a_p = p >> 2, u_p = p & 3;
    if (p < 20) {
        const vf4 tpr = *(const vf4*)&lds[L_T2R + p*64 + c4];
        const vf4 tpi = *(const vf4*)&lds[L_T2I + p*64 + c4];
#pragma unroll
        for (int e = 0; e < 4; ++e) {
            ppr[e] = tpr[e]*is2r[e] - tpi[e]*is2i[e];
            ppi[e] = tpr[e]*is2i[e] + tpi[e]*is2r[e];
        }
    }

#pragma unroll
    for (int qi = 0; qi < 6; ++qi) {
        const int q = 4*qi + h;
        if (q > 20) continue;                       // only h==0 reaches q=20
        vf4 ar4, ai4;
        const bool do_sc = (p < 20) && (h == u_p) && (qi < 5);
        if (do_sc) {                                // A1[a_p][qi] addend, 4 cols
            if (a_p < 4) {
#pragma unroll
                for (int e = 0; e < 4; ++e) {
                    const int jc = c4 + e;
                    const float par = SC(8+a_p, u_p, jc), pai = SC(12+a_p, u_p, jc);
                    if (qi < 4) {
                        const float tbr = SC(qi, u_p, jc), tbi = SC(4+qi, u_p, jc);
                        float vr = par*tbr + pai*tbi;   // P1[a]*conj(T1[b])
                        float vi = pai*tbr - par*tbi;
                        if (qi == a_p) { vr += SC(16+a_p, u_p, jc); vi += SC(20+a_p, u_p, jc); }
                        sar[e] = vr; sai[e] = vi;
                    } else { sar[e] = -par; sai[e] = -pai; }   // -P1[a]
                }
            } else {
#pragma unroll
                for (int e = 0; e < 4; ++e) {
                    const int jc = c4 + e;
                    if (qi < 4) { sar[e] = -SC(8+qi, u_p, jc); sai[e] = SC(12+qi, u_p, jc); }
                    else        { sar[e] =  SC(24,   u_p, jc); sai[e] = SC(25,   u_p, jc); }
                }
            }
        }
        if (p == 20) {
            if (q < 20) {
                const vf4 tr = *(const vf4*)&lds[L_T2R + q*64 + c4];
                const vf4 ti = *(const vf4*)&lds[L_T2I + q*64 + c4];
#pragma unroll
                for (int e = 0; e < 4; ++e) {
                    ar4[e] = -(tr[e]*is2r[e] - ti[e]*is2i[e]);   // -conj(P2[q])
                    ai4[e] =  (tr[e]*is2i[e] + ti[e]*is2r[e]);
                }
            } else { ar4 = is2r; ai4 = is2i; }      // 1/S2
        } else {
            if (q < 20) {
                const vf4 tr = *(const vf4*)&lds[L_T2R + q*64 + c4];
                const vf4 ti = *(const vf4*)&lds[L_T2I + q*64 + c4];
#pragma unroll
                for (int e = 0; e < 4; ++e) {
                    float vr = ppr[e]*tr[e] + ppi[e]*ti[e];   // P2[p]*conj(T2[q])
                    float vi = ppi[e]*tr[e] - ppr[e]*ti[e];
                    if (do_sc) { vr += sar[e]; vi += sai[e]; }
                    ar4[e] = vr; ai4[e] = vi;
                }
            } else {
#pragma unroll
                for (int e = 0; e < 4; ++e) { ar4[e] = -ppr[e]; ai4[e] = -ppi[e]; } // -P2[p]
            }
        }
        __builtin_nontemporal_store(ar4, (vf4*)(out + (p*21+q)*N2 + j4));
        __builtin_nontemporal_store(ai4, (vf4*)(out + OUT_AIM + (p*21+q)*N2 + j4));
        const vf4 zr4 = *(const vf4*)(zre + q*N2 + j4);
        const vf4 zi4 = *(const vf4*)(zim + q*N2 + j4);
#pragma unroll
        for (int e = 0; e < 4; ++e) {
            zar[e] += zr4[e]*ar4[e] - zi4[e]*ai4[e];
            zai[e] += zr4[e]*ai4[e] + zi4[e]*ar4[e];
        }
    }

    // reduce z over the 4 h-groups, remap to 1 col/lane, scalar NT store
#pragma unroll
    for (int e = 0; e < 4; ++e) {
        zar[e] += __shfl_xor(zar[e], 16, 64);  zar[e] += __shfl_xor(zar[e], 32, 64);
        zai[e] += __shfl_xor(zai[e], 16, 64);  zai[e] += __shfl_xor(zai[e], 32, 64);
    }
    {
        const int src = l >> 2;                     // lane holding col j0+l
        const float r0 = __shfl(zar[0], src, 64), r1 = __shfl(zar[1], src, 64);
        const float r2 = __shfl(zar[2], src, 64), r3 = __shfl(zar[3], src, 64);
        const float i0 = __shfl(zai[0], src, 64), i1 = __shfl(zai[1], src, 64);
        const float i2 = __shfl(zai[2], src, 64), i3 = __shfl(zai[3], src, 64);
        const int e = l & 3;
        const float zvr = e==0 ? r0 : e==1 ? r1 : e==2 ? r2 : r3;
        const float zvi = e==0 ? i0 : e==1 ? i1 : e==2 ? i2 : i3;
        __builtin_nontemporal_store(zvr, out + OUT_ZRE + p*N2 + j0 + l);
        __builtin_nontemporal_store(zvi, out + OUT_ZIM + p*N2 + j0 + l);
    }

    // ================= logdet block reduction (y==0 only) =================
    if (y0) {
        float v = ld;
#pragma unroll
        for (int off = 32; off > 0; off >>= 1) v += __shfl_down(v, off, 64);
        __syncthreads();                            // LDS reuse guard
        if (jl == 0) lds[L_RED + g] = v;
        __syncthreads();
        if (t == 0) {
            double s = 0.0;
#pragma unroll
            for (int w = 0; w < 7; ++w) s += (double)lds[L_RED + w];
            ld_partial[blockIdx.x] = s;
        }
    }
}

__global__ void finalize_kernel(const double* __restrict__ part,
                                float* __restrict__ out) {
    double v = part[threadIdx.x];                   // 256 partials
#pragma unroll
    for (int off = 32; off > 0; off >>= 1) v += __shfl_down(v, off, 64);
    __shared__ double wsum[4];
    if ((threadIdx.x & 63) == 0) wsum[threadIdx.x >> 6] = v;
    __syncthreads();
    if (threadIdx.x == 0)
        out[OUT_LD] = (float)(wsum[0] + wsum[1] + wsum[2] + wsum[3]);
}

extern "C" void kernel_launch(void* const* d_in, const int* in_sizes, int n_in,
                              void* d_out, int out_size, void* d_ws, size_t ws_size,
                              hipStream_t stream)
{
    const float* l00r = (const float*)d_in[0];
    const float* l00i = (const float*)d_in[1];
    const float* l01r = (const float*)d_in[2];
    const float* l01i = (const float*)d_in[3];
    const float* l02r = (const float*)d_in[4];
    const float* l02i = (const float*)d_in[5];
    const float* l11r = (const float*)d_in[6];
    const float* l11i = (const float*)d_in[7];
    const float* l12r = (const float*)d_in[8];
    const float* l12i = (const float*)d_in[9];
    const float* l22r = (const float*)d_in[10];
    const float* l22i = (const float*)d_in[11];
    const float* zre  = (const float*)d_in[12];
    const float* zim  = (const float*)d_in[13];
    float*  out        = (float*)d_out;
    double* ld_partial = (double*)d_ws;             // 256 doubles, written each call

    fused_kernel<<<dim3(N2/64, 3), dim3(448), 0, stream>>>(
        l00r,l00i,l01r,l01i,l02r,l02i,l11r,l11i,l12r,l12i,l22r,l22i,
        zre,zim, out, ld_partial);
    finalize_kernel<<<1, 256, 0, stream>>>(ld_partial, out);
}